// Round 1
// baseline (541.052 us; speedup 1.0000x reference)
//
#include <hip/hip_runtime.h>

// Hardcoded per-gas 16-band spectral filters (h2o, o3, co2, o2, n2o, ch4, co).
// FILT[g][ch] = F16[g][ch/3]  (each band repeated 3x along channel).
__device__ __constant__ float F16[7][16] = {
    {1,1,1,1,1,1,1,1,1,1,1,1,1,0,1,1},  // h2o
    {0,0,0,1,1,0,1,1,0,0,0,0,1,0,0,0},  // o3
    {0,0,1,1,1,1,1,1,0,0,0,1,1,1,1,0},  // co2
    {1,0,0,0,0,0,0,0,0,0,1,0,0,0,0,0},  // o2
    {0,0,1,0,0,0,0,1,1,0,0,0,1,0,1,0},  // n2o
    {0,0,0,0,0,0,0,0,1,0,0,0,0,0,0,1},  // ch4
    {0,0,0,0,0,0,0,1,0,0,0,0,1,0,0,0},  // co
};

#define SPB 64                 // samples per block
#define OPS 432                // outputs per sample = 48*9
#define BLOCK_OUT (SPB * OPS)  // 27648 floats per block

// out[n, ch, j] = M[ch*9+j] * s[n, j]
//   M[ch*9+j] = exp(w_lin[j*48+ch]) * (j<2 ? 1 : F16[j-2][ch/3])
//   s[n, j]   = c[n,j] * (j<2 ? 1 : sigmoid(MLP_{j-2}(t_p[n])))
__global__ __launch_bounds__(256) void tau_kernel(
    const float* __restrict__ t_p, const float* __restrict__ c,
    const float* __restrict__ w_lin,
    const float* __restrict__ W1, const float* __restrict__ b1,
    const float* __restrict__ W2, const float* __restrict__ b2,
    const float* __restrict__ W3, const float* __restrict__ b3,
    const float* __restrict__ Wo, const float* __restrict__ bo,
    float* __restrict__ out, int N)
{
    __shared__ __align__(16) float M[OPS];
    __shared__ float s[SPB][9];

    const int tid = threadIdx.x;
    const int n0  = blockIdx.x * SPB;
    const int nsamp = (N - n0 < SPB) ? (N - n0) : SPB;

    // ---- Phase 0: build the 432-entry M table (cheap: 432 expf/block) ----
    for (int r = tid; r < OPS; r += 256) {
        int ch = r / 9;
        int j  = r - ch * 9;
        float coef = expf(w_lin[j * 48 + ch]);
        float f = (j < 2) ? 1.0f : F16[j - 2][ch / 3];
        M[r] = coef * f;
    }

    // ---- Phase 1: per-(gas, sample) tiny MLP -> s_lds ----
    // item = g*64 + ln; g is wave-uniform (64 lanes per gas).
    for (int item = tid; item < 7 * SPB; item += 256) {
        int g  = item >> 6;
        int ln = item & 63;
        if (ln >= nsamp) continue;
        int n = n0 + ln;

        float t0 = t_p[2 * n];
        float t1 = t_p[2 * n + 1];

        const float* w1  = W1 + g * 12;   // [6][2]
        const float* bb1 = b1 + g * 6;
        float h1[6];
#pragma unroll
        for (int k = 0; k < 6; k++) {
            float v = fmaf(w1[2 * k], t0, fmaf(w1[2 * k + 1], t1, bb1[k]));
            h1[k] = v > 0.f ? v : 0.f;
        }
        const float* w2  = W2 + g * 24;   // [4][6]
        const float* bb2 = b2 + g * 4;
        float h2[4];
#pragma unroll
        for (int o = 0; o < 4; o++) {
            float v = bb2[o];
#pragma unroll
            for (int h = 0; h < 6; h++) v = fmaf(w2[o * 6 + h], h1[h], v);
            h2[o] = v > 0.f ? v : 0.f;
        }
        const float* w3  = W3 + g * 16;   // [4][4]
        const float* bb3 = b3 + g * 4;
        float h3[4];
#pragma unroll
        for (int o = 0; o < 4; o++) {
            float v = bb3[o];
#pragma unroll
            for (int h = 0; h < 4; h++) v = fmaf(w3[o * 4 + h], h2[h], v);
            h3[o] = v > 0.f ? v : 0.f;
        }
        float x = bo[g];
#pragma unroll
        for (int h = 0; h < 4; h++) x = fmaf(Wo[g * 4 + h], h3[h], x);
        float ke = 1.0f / (1.0f + expf(-x));

        s[ln][2 + g] = c[9 * n + 2 + g] * ke;
        if (g == 0) {
            s[ln][0] = c[9 * n + 0];
            s[ln][1] = c[9 * n + 1];
        }
    }

    __syncthreads();

    // ---- Phase 2: coalesced float4 streaming stores ----
    // 432 % 4 == 0 -> a float4 never straddles a sample boundary.
    const size_t base = (size_t)blockIdx.x * BLOCK_OUT;
    const int lim = nsamp * OPS;
    for (int l = tid * 4; l < lim; l += 1024) {
        int ln = l / OPS;
        int r  = l - ln * OPS;       // r % 4 == 0
        int j0 = r % 9;

        float4 m = *reinterpret_cast<const float4*>(&M[r]);
        int j1 = j0 + 1; if (j1 >= 9) j1 -= 9;
        int j2 = j0 + 2; if (j2 >= 9) j2 -= 9;
        int j3 = j0 + 3; if (j3 >= 9) j3 -= 9;

        float4 v;
        v.x = m.x * s[ln][j0];
        v.y = m.y * s[ln][j1];
        v.z = m.z * s[ln][j2];
        v.w = m.w * s[ln][j3];
        *reinterpret_cast<float4*>(out + base + l) = v;
    }
}

extern "C" void kernel_launch(void* const* d_in, const int* in_sizes, int n_in,
                              void* d_out, int out_size, void* d_ws, size_t ws_size,
                              hipStream_t stream) {
    const float* t_p   = (const float*)d_in[0];
    const float* c     = (const float*)d_in[1];
    const float* w_lin = (const float*)d_in[2];
    const float* W1    = (const float*)d_in[3];
    const float* b1    = (const float*)d_in[4];
    const float* W2    = (const float*)d_in[5];
    const float* b2    = (const float*)d_in[6];
    const float* W3    = (const float*)d_in[7];
    const float* b3    = (const float*)d_in[8];
    const float* Wo    = (const float*)d_in[9];
    const float* bo    = (const float*)d_in[10];
    float* out = (float*)d_out;

    int N = in_sizes[0] / 2;               // 262144
    int blocks = (N + SPB - 1) / SPB;      // 4096
    tau_kernel<<<blocks, 256, 0, stream>>>(t_p, c, w_lin, W1, b1, W2, b2,
                                           W3, b3, Wo, bo, out, N);
}

// Round 3
// 477.488 us; speedup vs baseline: 1.1331x; 1.1331x over previous
//
#include <hip/hip_runtime.h>

typedef float f4 __attribute__((ext_vector_type(4)));  // native vec for nontemporal builtin

// Hardcoded per-gas 16-band spectral filters (h2o, o3, co2, o2, n2o, ch4, co).
// FILT[g][ch] = F16[g][ch/3]  (each band repeated 3x along channel).
__device__ __constant__ float F16[7][16] = {
    {1,1,1,1,1,1,1,1,1,1,1,1,1,0,1,1},  // h2o
    {0,0,0,1,1,0,1,1,0,0,0,0,1,0,0,0},  // o3
    {0,0,1,1,1,1,1,1,0,0,0,1,1,1,1,0},  // co2
    {1,0,0,0,0,0,0,0,0,0,1,0,0,0,0,0},  // o2
    {0,0,1,0,0,0,0,1,1,0,0,0,1,0,1,0},  // n2o
    {0,0,0,0,0,0,0,0,1,0,0,0,0,0,0,1},  // ch4
    {0,0,0,0,0,0,0,1,0,0,0,0,1,0,0,0},  // co
};

#define SPB 64                 // samples per block
#define OPS 432                // outputs per sample = 48*9
#define BLOCK_OUT (SPB * OPS)  // 27648 floats per block
#define Q_PER_BLOCK (BLOCK_OUT / 4)   // 6912 float4 stores per block
#define SROW 40                // padded s36 row stride (16B-aligned, bank-spread)

// out[n, ch, j] = M[ch*9+j] * s[n, j]
//   M[ch*9+j] = exp(w_lin[j*48+ch]) * (j<2 ? 1 : F16[j-2][ch/3])
//   s[n, j]   = c[n,j] * (j<2 ? 1 : sigmoid(MLP_{j-2}(t_p[n])))
// s36[ln][m] = s[ln][m % 9] for m in [0,36): any aligned float4 of the
// output maps to ONE contiguous ds_read_b128 of s36.
__global__ __launch_bounds__(256) void tau_kernel(
    const float* __restrict__ t_p, const float* __restrict__ c,
    const float* __restrict__ w_lin,
    const float* __restrict__ W1, const float* __restrict__ b1,
    const float* __restrict__ W2, const float* __restrict__ b2,
    const float* __restrict__ W3, const float* __restrict__ b3,
    const float* __restrict__ Wo, const float* __restrict__ bo,
    float* __restrict__ out, int N)
{
    __shared__ __align__(16) float M[OPS];
    __shared__ __align__(16) float s36[SPB][SROW];

    const int tid = threadIdx.x;
    const int n0  = blockIdx.x * SPB;
    const int nsamp = (N - n0 < SPB) ? (N - n0) : SPB;

    // ---- Phase 0: build the 432-entry M table (432 expf/block) ----
    for (int r = tid; r < OPS; r += 256) {
        int ch = r / 9;
        int j  = r - ch * 9;
        float coef = expf(w_lin[j * 48 + ch]);
        float f = (j < 2) ? 1.0f : F16[j - 2][ch / 3];
        M[r] = coef * f;
    }

    // ---- Phase 1: per-(gas, sample) tiny MLP -> s36 (4x replicated) ----
    // item = g*64 + ln; g is wave-uniform (64 lanes per gas).
    for (int item = tid; item < 7 * SPB; item += 256) {
        int g  = item >> 6;
        int ln = item & 63;
        if (ln >= nsamp) continue;
        int n = n0 + ln;

        float t0 = t_p[2 * n];
        float t1 = t_p[2 * n + 1];

        const float* w1  = W1 + g * 12;   // [6][2]
        const float* bb1 = b1 + g * 6;
        float h1[6];
#pragma unroll
        for (int k = 0; k < 6; k++) {
            float v = fmaf(w1[2 * k], t0, fmaf(w1[2 * k + 1], t1, bb1[k]));
            h1[k] = v > 0.f ? v : 0.f;
        }
        const float* w2  = W2 + g * 24;   // [4][6]
        const float* bb2 = b2 + g * 4;
        float h2[4];
#pragma unroll
        for (int o = 0; o < 4; o++) {
            float v = bb2[o];
#pragma unroll
            for (int h = 0; h < 6; h++) v = fmaf(w2[o * 6 + h], h1[h], v);
            h2[o] = v > 0.f ? v : 0.f;
        }
        const float* w3  = W3 + g * 16;   // [4][4]
        const float* bb3 = b3 + g * 4;
        float h3[4];
#pragma unroll
        for (int o = 0; o < 4; o++) {
            float v = bb3[o];
#pragma unroll
            for (int h = 0; h < 4; h++) v = fmaf(w3[o * 4 + h], h2[h], v);
            h3[o] = v > 0.f ? v : 0.f;
        }
        float x = bo[g];
#pragma unroll
        for (int h = 0; h < 4; h++) x = fmaf(Wo[g * 4 + h], h3[h], x);
        float ke = 1.0f / (1.0f + expf(-x));

        float sv = c[9 * n + 2 + g] * ke;
        int j = 2 + g;
#pragma unroll
        for (int k = 0; k < 4; k++) s36[ln][j + 9 * k] = sv;
        if (g == 0) {
            float c0 = c[9 * n + 0];
            float c1 = c[9 * n + 1];
#pragma unroll
            for (int k = 0; k < 4; k++) {
                s36[ln][0 + 9 * k] = c0;
                s36[ln][1 + 9 * k] = c1;
            }
        }
    }

    __syncthreads();

    // ---- Phase 2: coalesced nontemporal float4 streaming stores ----
    const size_t base = (size_t)blockIdx.x * BLOCK_OUT;
    f4* __restrict__ outv = reinterpret_cast<f4*>(out + base);

    if (nsamp == SPB) {
        // Full block (always, since N % 64 == 0): constant trip count 27.
#pragma unroll 9
        for (int i = 0; i < Q_PER_BLOCK / 256; ++i) {
            int q  = tid + 256 * i;       // float4 index in [0, 6912)
            int ln = q / 108;             // sample within block
            int rq = q - ln * 108;        // float4 index within sample
            int m  = 4 * (rq % 9);        // replicated-s offset, 16B aligned

            f4 mm = *reinterpret_cast<const f4*>(&M[4 * rq]);
            f4 ss = *reinterpret_cast<const f4*>(&s36[ln][m]);
            f4 v = mm * ss;
            __builtin_nontemporal_store(v, outv + q);
        }
    } else {
        // Tail block (not hit for N=262144): simple scalar path.
        int lim = nsamp * OPS;
        for (int l = tid; l < lim; l += 256) {
            int ln = l / OPS;
            int r  = l - ln * OPS;
            out[base + l] = M[r] * s36[ln][r % 9];
        }
    }
}

extern "C" void kernel_launch(void* const* d_in, const int* in_sizes, int n_in,
                              void* d_out, int out_size, void* d_ws, size_t ws_size,
                              hipStream_t stream) {
    const float* t_p   = (const float*)d_in[0];
    const float* c     = (const float*)d_in[1];
    const float* w_lin = (const float*)d_in[2];
    const float* W1    = (const float*)d_in[3];
    const float* b1    = (const float*)d_in[4];
    const float* W2    = (const float*)d_in[5];
    const float* b2    = (const float*)d_in[6];
    const float* W3    = (const float*)d_in[7];
    const float* b3    = (const float*)d_in[8];
    const float* Wo    = (const float*)d_in[9];
    const float* bo    = (const float*)d_in[10];
    float* out = (float*)d_out;

    int N = in_sizes[0] / 2;               // 262144
    int blocks = (N + SPB - 1) / SPB;      // 4096
    tau_kernel<<<blocks, 256, 0, stream>>>(t_p, c, w_lin, W1, b1, W2, b2,
                                           W3, b3, Wo, bo, out, N);
}